// Round 2
// baseline (6128.968 us; speedup 1.0000x reference)
//
#include <hip/hip_runtime.h>

#define B_SZ    32
#define IN_DIM  1024
#define K_TOTAL 525824          // 1024 + 524800
#define OUT_DIM 512
#define BK      512
#define NCHUNK  1027            // K_TOTAL / BK exactly
#define KGROUPS 32
#define OGROUPS 16              // 512 outputs / 32 per block

// out[b*512+o] = bias[o]  (re-initialized every launch; atomics add on top)
__global__ void bias_init_kernel(const float* __restrict__ bias, float* __restrict__ out)
{
    int i = blockIdx.x * 256 + threadIdx.x;     // 16384 total
    out[i] = bias[i & (OUT_DIM - 1)];
}

__global__ __launch_bounds__(512, 4)
void qgemm_kernel(const float* __restrict__ x,
                  const float* __restrict__ W,
                  float* __restrict__ out)
{
    __shared__ float xt[B_SZ][BK];              // 64 KB

    const int tid   = threadIdx.x;
    const int lane  = tid & 63;
    const int wave  = tid >> 6;                 // 0..7
    const int ogrp  = wave >> 1;                // 0..3
    const int bhalf = wave & 1;                 // 0..1

    const int og = blockIdx.x / KGROUPS;        // 0..15
    const int kg = blockIdx.x % KGROUPS;        // 0..31

    const int o_base = og * 32 + ogrp * 8;
    const int b_base = bhalf * 16;

    float acc[16][8];
    #pragma unroll
    for (int b = 0; b < 16; ++b)
        #pragma unroll
        for (int o = 0; o < 8; ++o) acc[b][o] = 0.f;

    for (int chunk = kg; chunk < NCHUNK; chunk += KGROUPS) {
        const int k = chunk * BK + tid;

        __syncthreads();                        // previous compute done before overwrite
        if (k < IN_DIM) {
            // linear features (chunks 0 and 1 exactly)
            #pragma unroll
            for (int b = 0; b < B_SZ; ++b)
                xt[b][tid] = x[b * IN_DIM + k];
        } else {
            // quadratic feature t -> (r,c), row-major triu incl. diagonal
            const int t = k - IN_DIM;
            // off(r) = r*1024 - r(r-1)/2 ; invert: r = floor((2049 - sqrt(2049^2 - 8t))/2)
            double disc = 4198401.0 - 8.0 * (double)t;
            int r = (int)((2049.0 - sqrt(disc)) * 0.5);
            int off = r * IN_DIM - ((r * (r - 1)) >> 1);
            if (t < off) {
                --r; off = r * IN_DIM - ((r * (r - 1)) >> 1);
            } else if (t >= off + (IN_DIM - r)) {
                off += IN_DIM - r; ++r;
            }
            const int c = r + (t - off);
            #pragma unroll
            for (int b = 0; b < B_SZ; ++b)
                xt[b][tid] = x[b * IN_DIM + r] * x[b * IN_DIM + c];
        }
        __syncthreads();

        const float* wbase = W + (size_t)o_base * K_TOTAL + (size_t)chunk * BK;
        #pragma unroll
        for (int pass = 0; pass < 2; ++pass) {
            const int kk = pass * 256 + lane * 4;
            float4 wv[8];
            #pragma unroll
            for (int o = 0; o < 8; ++o)
                wv[o] = *(const float4*)(wbase + (size_t)o * K_TOTAL + kk);
            #pragma unroll
            for (int b = 0; b < 16; ++b) {
                float4 xv = *(const float4*)&xt[b_base + b][kk];
                #pragma unroll
                for (int o = 0; o < 8; ++o)
                    acc[b][o] += xv.x * wv[o].x + xv.y * wv[o].y
                               + xv.z * wv[o].z + xv.w * wv[o].w;
            }
        }
    }

    // 64-lane butterfly reduce (each acc element summed across the wave's k-slices)
    #pragma unroll
    for (int b = 0; b < 16; ++b)
        #pragma unroll
        for (int o = 0; o < 8; ++o) {
            float v = acc[b][o];
            #pragma unroll
            for (int m = 1; m < 64; m <<= 1)
                v += __shfl_xor(v, m);
            acc[b][o] = v;
        }

    if (lane == 0) {
        #pragma unroll
        for (int b = 0; b < 16; ++b)
            #pragma unroll
            for (int o = 0; o < 8; ++o)
                atomicAdd(&out[(b_base + b) * OUT_DIM + o_base + o], acc[b][o]);
    }
}

extern "C" void kernel_launch(void* const* d_in, const int* in_sizes, int n_in,
                              void* d_out, int out_size, void* d_ws, size_t ws_size,
                              hipStream_t stream)
{
    const float* x    = (const float*)d_in[0];   // [32,64,16] = [32,1024] fp32
    const float* W    = (const float*)d_in[1];   // [512, 525824] fp32
    const float* bias = (const float*)d_in[2];   // [512] fp32
    float* out = (float*)d_out;                  // [32,512] fp32

    hipLaunchKernelGGL(bias_init_kernel, dim3(64), dim3(256), 0, stream, bias, out);
    hipLaunchKernelGGL(qgemm_kernel, dim3(OGROUPS * KGROUPS), dim3(512), 0, stream,
                       x, W, out);
}

// Round 3
// 827.463 us; speedup vs baseline: 7.4069x; 7.4069x over previous
//
#include <hip/hip_runtime.h>

#define B_SZ    32
#define IN_DIM  1024
#define K_TOTAL 525824          // 1024 linear + 524800 triu
#define OUT_DIM 512
#define BK      512
#define NCHUNK  1027            // K_TOTAL / BK exactly
#define KGROUPS 16
#define OGROUPS 32              // 16 outputs per block

// out[b*512+o] = bias[o]  (re-initialized every launch; atomics add on top)
__global__ void bias_init_kernel(const float* __restrict__ bias, float* __restrict__ out)
{
    int i = blockIdx.x * 256 + threadIdx.x;     // 16384 total
    out[i] = bias[i & (OUT_DIM - 1)];
}

__global__ __launch_bounds__(512, 2)            // VGPR cap 256 -> NO spill
void qgemm_kernel(const float* __restrict__ x,
                  const float* __restrict__ W,
                  float* __restrict__ out)
{
    __shared__ float xt[B_SZ][BK];              // 64 KB feature tile

    const int tid  = threadIdx.x;
    const int lane = tid & 63;
    const int wave = tid >> 6;                  // 0..7
    const int bgrp = wave & 3;                  // 0..3  -> 8 batches each
    const int ogrp = wave >> 2;                 // 0..1  -> 8 outputs each

    const int og = blockIdx.x & (OGROUPS - 1);  // 0..31
    const int kg = blockIdx.x / OGROUPS;        // 0..15

    const int o_base = og * 16 + ogrp * 8;
    const int b_base = bgrp * 8;

    float acc[8][8];                            // 64 VGPRs
    #pragma unroll
    for (int i = 0; i < 8; ++i)
        #pragma unroll
        for (int o = 0; o < 8; ++o) acc[i][o] = 0.f;

    for (int chunk = kg; chunk < NCHUNK; chunk += KGROUPS) {
        const int k = chunk * BK + tid;

        __syncthreads();                        // readers of previous tile done
        if (k < IN_DIM) {
            #pragma unroll
            for (int b = 0; b < B_SZ; ++b)
                xt[b][tid] = x[b * IN_DIM + k];
        } else {
            // flat triu index t -> (r,c), row-major incl. diagonal
            const int t = k - IN_DIM;
            double disc = 4198401.0 - 8.0 * (double)t;   // 2049^2 - 8t
            int r = (int)((2049.0 - sqrt(disc)) * 0.5);
            int off = r * IN_DIM - ((r * (r - 1)) >> 1);
            if (t < off) {
                --r; off = r * IN_DIM - ((r * (r - 1)) >> 1);
            } else if (t >= off + (IN_DIM - r)) {
                off += IN_DIM - r; ++r;
            }
            const int c = r + (t - off);
            #pragma unroll
            for (int b = 0; b < B_SZ; ++b)
                xt[b][tid] = x[b * IN_DIM + r] * x[b * IN_DIM + c];
        }
        __syncthreads();

        const float* wrow = W + (size_t)o_base * K_TOTAL + (size_t)chunk * BK;
        #pragma unroll
        for (int pass = 0; pass < 2; ++pass) {
            const int kk = pass * 256 + lane * 4;

            float4 wv[8];                       // 32 VGPRs, hoisted loads
            #pragma unroll
            for (int o = 0; o < 8; ++o)
                wv[o] = *(const float4*)(wrow + (size_t)o * K_TOTAL + kk);

            float4 xv[8];                       // 32 VGPRs
            #pragma unroll
            for (int i = 0; i < 8; ++i)
                xv[i] = *(const float4*)&xt[b_base + i][kk];

            #pragma unroll
            for (int o = 0; o < 8; ++o)
                #pragma unroll
                for (int i = 0; i < 8; ++i)
                    acc[i][o] += xv[i].x * wv[o].x + xv[i].y * wv[o].y
                               + xv[i].z * wv[o].z + xv[i].w * wv[o].w;
        }
    }

    // sum each acc element across the wave's 64 k-slices
    #pragma unroll
    for (int i = 0; i < 8; ++i)
        #pragma unroll
        for (int o = 0; o < 8; ++o) {
            float v = acc[i][o];
            #pragma unroll
            for (int m = 1; m < 64; m <<= 1)
                v += __shfl_xor(v, m);
            acc[i][o] = v;
        }

    if (lane == 0) {
        #pragma unroll
        for (int i = 0; i < 8; ++i)
            #pragma unroll
            for (int o = 0; o < 8; ++o)
                atomicAdd(&out[(b_base + i) * OUT_DIM + o_base + o], acc[i][o]);
    }
}

extern "C" void kernel_launch(void* const* d_in, const int* in_sizes, int n_in,
                              void* d_out, int out_size, void* d_ws, size_t ws_size,
                              hipStream_t stream)
{
    const float* x    = (const float*)d_in[0];   // [32,64,16] = [32,1024] fp32
    const float* W    = (const float*)d_in[1];   // [512, 525824] fp32
    const float* bias = (const float*)d_in[2];   // [512] fp32
    float* out = (float*)d_out;                  // [32,512] fp32

    hipLaunchKernelGGL(bias_init_kernel, dim3(64), dim3(256), 0, stream, bias, out);
    hipLaunchKernelGGL(qgemm_kernel, dim3(OGROUPS * KGROUPS), dim3(512), 0, stream,
                       x, W, out);
}